// Round 7
// baseline (23.829 us; speedup 1.0000x reference)
//
#include <hip/hip_runtime.h>
#include <math.h>

#define NQ    12
#define TPB   512
#define AMPS  8
#define DEPTH 4

typedef float v2f __attribute__((ext_vector_type(2)));

__device__ __forceinline__ v2f splat(float s) { return (v2f){s, s}; }
__device__ __forceinline__ v2f vfma(v2f a, v2f b, v2f c) {
    return __builtin_elementwise_fma(a, b, c);   // -> v_pk_fma_f32
}

// readlane broadcast of a float (literal lane index), pure VALU/SALU
#define RL(v, l) __uint_as_float(__builtin_amdgcn_readlane(__float_as_uint(v), (l)))

// ---- cross-lane helpers (VALU pipe) ------------------------------------
template<int CTRL>
__device__ __forceinline__ float dppf(float v) {
    int r = __builtin_amdgcn_update_dpp(0, __float_as_int(v), CTRL, 0xF, 0xF, true);
    return __int_as_float(r);
}
template<int CTRL>
__device__ __forceinline__ v2f dpp2(v2f v) {
    v2f r;
    r.x = dppf<CTRL>(v.x);
    r.y = dppf<CTRL>(v.y);
    return r;
}

#if __has_builtin(__builtin_amdgcn_permlane32_swap)
#define HAVE_PL32 1
#else
#define HAVE_PL32 0
#endif
#if __has_builtin(__builtin_amdgcn_permlane16_swap)
#define HAVE_PL16 1
#else
#define HAVE_PL16 0
#endif

__device__ __forceinline__ void split32v(v2f v, v2f& v0, v2f& v1) {
#if HAVE_PL32
    auto rx = __builtin_amdgcn_permlane32_swap(__float_as_uint(v.x), __float_as_uint(v.x), false, false);
    auto ry = __builtin_amdgcn_permlane32_swap(__float_as_uint(v.y), __float_as_uint(v.y), false, false);
    v0 = (v2f){__uint_as_float(rx[0]), __uint_as_float(ry[0])};
    v1 = (v2f){__uint_as_float(rx[1]), __uint_as_float(ry[1])};
#else
    v2f p;
    p.x = __shfl_xor(v.x, 32, 64);
    p.y = __shfl_xor(v.y, 32, 64);
    int bit = (__lane_id() >> 5) & 1;
    v0 = bit ? p : v;
    v1 = bit ? v : p;
#endif
}
__device__ __forceinline__ void split16v(v2f v, v2f& v0, v2f& v1) {
#if HAVE_PL16
    auto rx = __builtin_amdgcn_permlane16_swap(__float_as_uint(v.x), __float_as_uint(v.x), false, false);
    auto ry = __builtin_amdgcn_permlane16_swap(__float_as_uint(v.y), __float_as_uint(v.y), false, false);
    v0 = (v2f){__uint_as_float(rx[0]), __uint_as_float(ry[0])};
    v1 = (v2f){__uint_as_float(rx[1]), __uint_as_float(ry[1])};
#else
    v2f p;
    p.x = __shfl_xor(v.x, 16, 64);
    p.y = __shfl_xor(v.y, 16, 64);
    int bit = (__lane_id() >> 4) & 1;
    v0 = bit ? p : v;
    v1 = bit ? v : p;
#endif
}
__device__ __forceinline__ void split16(float v, float& v0, float& v1) {
#if HAVE_PL16
    auto r = __builtin_amdgcn_permlane16_swap(__float_as_uint(v), __float_as_uint(v), false, false);
    v0 = __uint_as_float(r[0]);
    v1 = __uint_as_float(r[1]);
#else
    float p = __shfl_xor(v, 16, 64);
    int bit = (__lane_id() >> 4) & 1;
    v0 = bit ? p : v;
    v1 = bit ? v : p;
#endif
}
__device__ __forceinline__ void split32(float v, float& v0, float& v1) {
#if HAVE_PL32
    auto r = __builtin_amdgcn_permlane32_swap(__float_as_uint(v), __float_as_uint(v), false, false);
    v0 = __uint_as_float(r[0]);
    v1 = __uint_as_float(r[1]);
#else
    float p = __shfl_xor(v, 32, 64);
    int bit = (__lane_id() >> 5) & 1;
    v0 = bit ? p : v;
    v1 = bit ? v : p;
#endif
}

// ---- butterfly variants (state: a[e] = (re, im) packed, AMPS=8) --------
template<int ST>
__device__ __forceinline__ void reg_wire(v2f a[AMPS], float cy, float sy) {
    const v2f cc = splat(cy), ss = splat(sy);
    #pragma unroll
    for (int e0 = 0; e0 < AMPS; ++e0) {
        if ((e0 & ST) == 0) {
            const int e1 = e0 | ST;
            v2f A0 = a[e0], A1 = a[e1];
            a[e0] = vfma(cc, A0, -(ss * A1));
            a[e1] = vfma(ss, A0, cc * A1);
        }
    }
}

template<int CTRL>
__device__ __forceinline__ void dpp_wire(v2f a[AMPS], float cy, float sy, int bit) {
    const v2f cc = splat(cy), sv = splat(bit ? sy : -sy);
    #pragma unroll
    for (int e = 0; e < AMPS; ++e) {
        v2f p = dpp2<CTRL>(a[e]);
        a[e] = vfma(sv, p, cc * a[e]);
    }
}

// mask 4: row_shr:4 sources lane i-4 (bit==1), row_shl:4 sources i+4 (bit==0)
__device__ __forceinline__ void xor4_wire(v2f a[AMPS], float cy, float sy, int bit) {
    const v2f cc = splat(cy), sv = splat(bit ? sy : -sy);
    #pragma unroll
    for (int e = 0; e < AMPS; ++e) {
        v2f pS = dpp2<0x114>(a[e]);
        v2f pL = dpp2<0x104>(a[e]);
        v2f p = bit ? pS : pL;
        a[e] = vfma(sv, p, cc * a[e]);
    }
}

template<bool IS32>
__device__ __forceinline__ void pl_wire(v2f a[AMPS], float cy, float sy, int bit) {
    const v2f ka = splat(bit ? sy : cy), kb = splat(bit ? cy : -sy);
    #pragma unroll
    for (int e = 0; e < AMPS; ++e) {
        v2f A0, A1;
        if constexpr (IS32) split32v(a[e], A0, A1);
        else                split16v(a[e], A0, A1);
        a[e] = vfma(ka, A0, kb * A1);
    }
}

__device__ __forceinline__ float wave_sum(float y) {
    y += dppf<0xB1>(y);
    y += dppf<0x4E>(y);
    y += dppf<0x124>(y);    // row_ror:4
    y += dppf<0x128>(y);    // row_ror:8
    float a, b;
    split16(y, a, b); y = a + b;
    split32(y, a, b); y = a + b;
    return y;
}

__global__ __launch_bounds__(TPB, 4) void qsim_kernel(
    const float* __restrict__ x,        // (512, 12)
    const float* __restrict__ params,   // (48, 12)
    const float* __restrict__ head_w,   // (2, 12)
    const float* __restrict__ head_b,   // (2,)
    float* __restrict__ out)            // (512, 2)
{
    __shared__ float4 exch[2][4][TPB];  // 64 KB double-buffered 8-way exchange
    __shared__ float  red[8][10];

    const int b = blockIdx.x;
    const int t = threadIdx.x;
    const int l = t & 63;

    // One sincos per lane (per wave, redundant across waves):
    //   lanes 0..47  -> RY angle (d,i): 0.5*params[l*12 + l%12]
    //   lanes 48..59 -> RX angle 0.5*x[b*12 + (l-48)]
    float cv, sv;
    {
        int li   = l % 12;
        int idx1 = (l < 48) ? (l * 12 + li) : 0;
        float v1 = params[idx1];
        int i2   = l - 48;
        int idx2 = (i2 >= 0 && i2 < 12) ? (b * 12 + i2) : 0;
        float v2 = x[idx2];
        float th = 0.5f * ((l < 48) ? v1 : ((i2 >= 0 && i2 < 12) ? v2 : 0.0f));
        __sincosf(th, &sv, &cv);
    }
    #define CY(d, w) RL(cv, (d) * 12 + (w))
    #define SY(d, w) RL(sv, (d) * 12 + (w))

    // state: amp index k = (t<<3)|e ; a[e] = (re, im)
    // wire w <-> k bit (11-w): wires 0,1,2 = t[8],t[7],t[6] (wave bits);
    // wires 3..8 = t[5:0] (lane bits); wires 9,10,11 = e[2:0].
    v2f a[AMPS];
    {
        float cx[12], sx[12];
        #pragma unroll
        for (int i = 0; i < 12; ++i) {
            cx[i] = RL(cv, 48 + i);
            sx[i] = RL(sv, 48 + i);
        }
        float P = 1.0f;
        #pragma unroll
        for (int j = 0; j < 9; ++j)
            P *= ((t >> (8 - j)) & 1) ? sx[j] : cx[j];
        int p = __popc(t) & 3;
        float ur = (p == 0) ? 1.f : ((p == 2) ? -1.f : 0.f);
        float ui = (p == 1) ? -1.f : ((p == 3) ? 1.f : 0.f);
        v2f u[4] = { (v2f){ur, ui}, (v2f){ui, -ur}, (v2f){-ur, -ui}, (v2f){-ui, ur} };
        #pragma unroll
        for (int e = 0; e < AMPS; ++e) {
            float m = P * ((e & 4) ? sx[9]  : cx[9])
                        * ((e & 2) ? sx[10] : cx[10])
                        * ((e & 1) ? sx[11] : cx[11]);
            a[e] = splat(m) * u[__popc(e) & 3];
        }
    }

    // CZ signs as +-1.0f (negate where popc(k & (k>>1)) odd)
    float czs[AMPS];
    #pragma unroll
    for (int e = 0; e < AMPS; ++e) {
        int k = (t << 3) | e;
        czs[e] = __int_as_float(0x3f800000u | (unsigned)((__popc(k & (k >> 1)) & 1) << 31));
    }

    #pragma unroll
    for (int d = 0; d < DEPTH; ++d) {
        // elem-bit wires 9,10,11 (strides 4,2,1)
        reg_wire<4>(a, CY(d, 9),  SY(d, 9));
        reg_wire<2>(a, CY(d, 10), SY(d, 10));
        reg_wire<1>(a, CY(d, 11), SY(d, 11));

        // lane-bit wires 3..8 (all VALU pipe)
        pl_wire<true >(a, CY(d, 3), SY(d, 3), (t >> 5) & 1);   // mask 32
        pl_wire<false>(a, CY(d, 4), SY(d, 4), (t >> 4) & 1);   // mask 16
        dpp_wire<0x128>(a, CY(d, 5), SY(d, 5), (t >> 3) & 1);  // mask 8
        xor4_wire      (a, CY(d, 6), SY(d, 6), (t >> 2) & 1);  // mask 4
        dpp_wire<0x4E >(a, CY(d, 7), SY(d, 7), (t >> 1) & 1);  // mask 2
        dpp_wire<0xB1 >(a, CY(d, 8), SY(d, 8), (t     ) & 1);  // mask 1

        // wave-bit wires 0,1,2 fused: 8-way exchange across t bits 8,7,6.
        // Double-buffered, one barrier per depth (R5 hazard argument).
        {
            const float c0 = CY(d, 0), s0r = SY(d, 0);
            const float c1 = CY(d, 1), s1r = SY(d, 1);
            const float c2 = CY(d, 2), s2r = SY(d, 2);
            const float ss0 = ((t >> 8) & 1) ? s0r : -s0r;   // wire0 = t[8]
            const float ss1 = ((t >> 7) & 1) ? s1r : -s1r;   // wire1 = t[7]
            const float ss2 = ((t >> 6) & 1) ? s2r : -s2r;   // wire2 = t[6]
            // K[m]: partner t ^ (m<<6); m bit0->wire2, bit1->wire1, bit2->wire0
            float K[8];
            K[0] = c0 * c1 * c2;
            K[1] = c0 * c1 * ss2;
            K[2] = c0 * ss1 * c2;
            K[3] = c0 * ss1 * ss2;
            K[4] = ss0 * c1 * c2;
            K[5] = ss0 * c1 * ss2;
            K[6] = ss0 * ss1 * c2;
            K[7] = ss0 * ss1 * ss2;

            float4 (*buf)[TPB] = exch[d & 1];
            #pragma unroll
            for (int j = 0; j < 4; ++j)
                buf[j][t] = make_float4(a[2*j].x, a[2*j].y, a[2*j+1].x, a[2*j+1].y);
            __syncthreads();

            v2f acc[AMPS];
            {
                const v2f k0 = splat(K[0]);
                #pragma unroll
                for (int e = 0; e < AMPS; ++e) acc[e] = k0 * a[e];
            }
            #pragma unroll
            for (int m = 1; m < 8; ++m) {
                const int p = t ^ (m << 6);
                const v2f km = splat(K[m]);
                #pragma unroll
                for (int j = 0; j < 4; ++j) {
                    float4 B = buf[j][p];
                    acc[2*j]   = vfma(km, (v2f){B.x, B.y}, acc[2*j]);
                    acc[2*j+1] = vfma(km, (v2f){B.z, B.w}, acc[2*j+1]);
                }
            }
            #pragma unroll
            for (int e = 0; e < AMPS; ++e) a[e] = acc[e];
        }

        // CZ signs (skip last depth: |amp|^2 unaffected)
        if (d < DEPTH - 1) {
            #pragma unroll
            for (int e = 0; e < AMPS; ++e)
                a[e] = a[e] * splat(czs[e]);
        }
    }

    // ---- reduction: T, lane-wire sums (3..8), elem-wire sums (9..11) ----
    v2f t2 = splat(0.f), q0 = splat(0.f), q1 = splat(0.f), q2 = splat(0.f);
    #pragma unroll
    for (int e = 0; e < AMPS; ++e) {
        v2f ae = a[e];
        t2 = vfma(ae, ae, t2);
        if (e & 4) q0 = vfma(ae, ae, q0);   // wire 9
        if (e & 2) q1 = vfma(ae, ae, q1);   // wire 10
        if (e & 1) q2 = vfma(ae, ae, q2);   // wire 11
    }
    float T = t2.x + t2.y;
    float v[10];
    v[0] = T;
    #pragma unroll
    for (int i = 0; i < 6; ++i)
        v[1 + i] = ((t >> (5 - i)) & 1) ? T : 0.0f;   // wires 3..8
    v[7] = q0.x + q0.y;
    v[8] = q1.x + q1.y;
    v[9] = q2.x + q2.y;

    #pragma unroll
    for (int i = 0; i < 10; ++i)
        v[i] = wave_sum(v[i]);

    if ((t & 63) == 0) {
        #pragma unroll
        for (int i = 0; i < 10; ++i) red[t >> 6][i] = v[i];
    }
    __syncthreads();

    if (t == 0) {
        float Tt = 0.f;
        #pragma unroll
        for (int w = 0; w < 8; ++w) Tt += red[w][0];
        float S[12];
        // wave-bit wires: wave w = t[8:6]; w[2]=wire0, w[1]=wire1, w[0]=wire2
        S[0] = red[4][0] + red[5][0] + red[6][0] + red[7][0];
        S[1] = red[2][0] + red[3][0] + red[6][0] + red[7][0];
        S[2] = red[1][0] + red[3][0] + red[5][0] + red[7][0];
        #pragma unroll
        for (int i = 0; i < 6; ++i) {
            float acc = 0.f;
            #pragma unroll
            for (int w = 0; w < 8; ++w) acc += red[w][1 + i];
            S[3 + i] = acc;
        }
        #pragma unroll
        for (int j = 0; j < 3; ++j) {
            float acc = 0.f;
            #pragma unroll
            for (int w = 0; w < 8; ++w) acc += red[w][7 + j];
            S[9 + j] = acc;
        }
        float l0 = head_b[0], l1 = head_b[1];
        #pragma unroll
        for (int w = 0; w < NQ; ++w) {
            float z = Tt - 2.0f * S[w];
            l0 += z * head_w[w];
            l1 += z * head_w[NQ + w];
        }
        float m = fmaxf(l0, l1);
        float lse = m + __logf(__expf(l0 - m) + __expf(l1 - m));
        out[b * 2 + 0] = l0 - lse;
        out[b * 2 + 1] = l1 - lse;
    }
}

extern "C" void kernel_launch(void* const* d_in, const int* in_sizes, int n_in,
                              void* d_out, int out_size, void* d_ws, size_t ws_size,
                              hipStream_t stream) {
    const float* x      = (const float*)d_in[0];
    const float* params = (const float*)d_in[1];
    const float* head_w = (const float*)d_in[2];
    const float* head_b = (const float*)d_in[3];
    float* out = (float*)d_out;

    const int batch = in_sizes[0] / NQ;   // 512
    qsim_kernel<<<batch, TPB, 0, stream>>>(x, params, head_w, head_b, out);
}